// Round 14
// baseline (427.090 us; speedup 1.0000x reference)
//
#include <hip/hip_runtime.h>
#include <hip/hip_bf16.h>
#include <math.h>

typedef short bf16x8 __attribute__((ext_vector_type(8)));
typedef float f32x4 __attribute__((ext_vector_type(4)));

#define HEADS 16
#define HDIM 64
#define HID 1024
#define B_ 4
#define T_ 2048
#define BT_ (B_*T_)      /* 8192 */
#define N1 (7*HID)       /* 7168 */
#define K2 (5*HID)       /* 5120 */

#define SM_SCALE_LOG2E 0.18033688011111793f   /* 0.125 * log2(e), folded into q at gemm1 */

__device__ __forceinline__ float bf2f(unsigned short u) {
  union { unsigned int i; float f; } c; c.i = ((unsigned int)u) << 16; return c.f;
}
__device__ __forceinline__ unsigned short f2bf(float f) {
  __hip_bfloat16 h = __float2bfloat16(f);
  return __builtin_bit_cast(unsigned short, h);
}
__device__ __forceinline__ unsigned int cvt_pk_bf16(float a, float b) {
  unsigned int r;
  asm("v_cvt_pk_bf16_f32 %0, %1, %2" : "=v"(r) : "v"(a), "v"(b));
  return r;
}
__device__ __forceinline__ float gelu_fast(float x) {
  float y = 0.7978845608028654f * (x + 0.044715f * x * x * x);
  float e = exp2f(y * 2.8853900817779268f);       // exp(2y)
  float t = 1.f - 2.f / (e + 1.f);                 // tanh(y)
  return 0.5f * x * (1.f + t);
}

typedef __attribute__((address_space(1))) const unsigned int gu32;
typedef __attribute__((address_space(3))) unsigned int lu32;
__device__ __forceinline__ void async16(const void* g, void* l) {
  __builtin_amdgcn_global_load_lds((gu32*)g, (lu32*)l, 16, 0, 0);
}

// ---------------- transpose + cast: in [R][C] f32 -> out [C][R] bf16 ----------------
__global__ __launch_bounds__(256) void tcast_kernel(const float* __restrict__ in,
                                                    unsigned short* __restrict__ out,
                                                    int R, int C) {
  __shared__ float tile[64][65];
  int tx = threadIdx.x & 63;
  int ty = threadIdx.x >> 6;
  long r0 = (long)blockIdx.y * 64;
  long c0 = (long)blockIdx.x * 64;
#pragma unroll
  for (int i = 0; i < 16; i++) {
    int r = ty + i * 4;
    tile[r][tx] = in[(r0 + r) * C + c0 + tx];
  }
  __syncthreads();
#pragma unroll
  for (int i = 0; i < 16; i++) {
    int rr = ty + i * 4;
    out[(c0 + rr) * R + r0 + tx] = f2bf(tile[tx][rr]);
  }
}

// ---------------- LayerNorm f32 -> bf16 ----------------
__global__ __launch_bounds__(256) void ln_kernel(const float* __restrict__ x,
                                                 const float* __restrict__ g,
                                                 const float* __restrict__ b,
                                                 unsigned short* __restrict__ xn) {
  int row = blockIdx.x, tid = threadIdx.x;
  float4 v = reinterpret_cast<const float4*>(x + (long)row * HID)[tid];
  float s = v.x + v.y + v.z + v.w;
  float sq = v.x * v.x + v.y * v.y + v.z * v.z + v.w * v.w;
#pragma unroll
  for (int off = 32; off > 0; off >>= 1) { s += __shfl_down(s, off); sq += __shfl_down(sq, off); }
  __shared__ float red[8];
  int wid = tid >> 6, lane = tid & 63;
  if (lane == 0) { red[wid] = s; red[4 + wid] = sq; }
  __syncthreads();
  if (tid == 0) {
    red[0] = red[0] + red[1] + red[2] + red[3];
    red[4] = red[4] + red[5] + red[6] + red[7];
  }
  __syncthreads();
  float mean = red[0] * (1.f / HID);
  float var  = red[4] * (1.f / HID) - mean * mean;
  float rstd = rsqrtf(var + 1e-5f);
  float4 gv = reinterpret_cast<const float4*>(g)[tid];
  float4 bv = reinterpret_cast<const float4*>(b)[tid];
  ushort4 o;
  o.x = f2bf((v.x - mean) * rstd * gv.x + bv.x);
  o.y = f2bf((v.y - mean) * rstd * gv.y + bv.y);
  o.z = f2bf((v.z - mean) * rstd * gv.z + bv.z);
  o.w = f2bf((v.w - mean) * rstd * gv.w + bv.w);
  reinterpret_cast<ushort4*>(xn + (long)row * HID)[tid] = o;
}

// ---------------- GEMM core: 128x128, BK=32, DMA-staged dbuf, single barrier ----------
// Staging via global_load_lds width=16 (rule #21 pattern): LINEAR LDS dest (lane l ->
// row R0+(l>>2), slot l&3), per-lane INVERSE-SWIZZLED global source chunk
// (l&3)^((l>>3)&3), so LDS slot s of row r holds chunk s^((r>>1)&3) — identical to
// the R8-R10 convention; fragment reads (slot = lq^((r>>1)&3)) unchanged,
// conflict-free. Removes 4 global->reg loads + 4 ds_write_b128 per wave per K-step.
// Per K-step: {issue 4 DMA loads for tile t+1 into buf^1} || {8 ds_read + 16 MFMA on
// buf[cur]}, one barrier (its vmcnt drain lands after a full compute phase).
__device__ __forceinline__ void gemm_core_dma(const unsigned short* __restrict__ A,
                                              const unsigned short* __restrict__ BT,
                                              unsigned short* As, unsigned short* Bs,
                                              int K, int lda, int ldb,
                                              long row0, long col0,
                                              int lane, int wid, f32x4 (&acc)[4][4]) {
  int l15 = lane & 15, lq = lane >> 4;
  int d  = lane >> 2;                     // row within 16-row segment
  int ch = (lane & 3) ^ ((lane >> 3) & 3);  // inverse-swizzled source chunk
  int R0 = wid * 32;
  const unsigned short* aS0 = A + (row0 + R0 + d)      * (long)lda + ch * 8;
  const unsigned short* aS1 = A + (row0 + R0 + 16 + d) * (long)lda + ch * 8;
  const unsigned short* bS0 = BT + (col0 + R0 + d)      * (long)ldb + ch * 8;
  const unsigned short* bS1 = BT + (col0 + R0 + 16 + d) * (long)ldb + ch * 8;
  int wm = (wid & 1) * 64, wn = (wid >> 1) * 64;
  int NT = K / 32;

  // prologue: DMA tile 0 -> buf0
  async16(aS0, &As[R0 * 32]);
  async16(aS1, &As[(R0 + 16) * 32]);
  async16(bS0, &Bs[R0 * 32]);
  async16(bS1, &Bs[(R0 + 16) * 32]);
  __syncthreads();

  int cur = 0;
  for (int t = 0; t < NT; t++) {
    if (t + 1 < NT) {   // DMA tile t+1 into the other buffer (no reader this iter)
      long ko = (long)(t + 1) * 32;
      int bo = (cur ^ 1) * 4096;
      async16(aS0 + ko, &As[bo + R0 * 32]);
      async16(aS1 + ko, &As[bo + (R0 + 16) * 32]);
      async16(bS0 + ko, &Bs[bo + R0 * 32]);
      async16(bS1 + ko, &Bs[bo + (R0 + 16) * 32]);
    }
    const unsigned short* Asr = As + cur * 4096;
    const unsigned short* Bsr = Bs + cur * 4096;
    bf16x8 af[4], bfv[4];
#pragma unroll
    for (int m = 0; m < 4; m++) {
      int r = wm + m * 16 + l15;
      af[m] = *reinterpret_cast<const bf16x8*>(&Asr[r * 32 + (lq ^ ((r >> 1) & 3)) * 8]);
    }
#pragma unroll
    for (int n = 0; n < 4; n++) {
      int r = wn + n * 16 + l15;
      bfv[n] = *reinterpret_cast<const bf16x8*>(&Bsr[r * 32 + (lq ^ ((r >> 1) & 3)) * 8]);
    }
#pragma unroll
    for (int m = 0; m < 4; m++)
#pragma unroll
      for (int n = 0; n < 4; n++)
        acc[m][n] = __builtin_amdgcn_mfma_f32_16x16x32_bf16(af[m], bfv[n], acc[m][n], 0, 0, 0);
    __syncthreads();
    cur ^= 1;
  }
}

// ---------------- GEMM1 with fused rotary / V-transpose / GELU epilogue ----------
__global__ __launch_bounds__(256) void gemm1_fused(const unsigned short* __restrict__ A,
                                                   const unsigned short* __restrict__ BT,
                                                   unsigned short* __restrict__ q_r,
                                                   unsigned short* __restrict__ k_r,
                                                   unsigned short* __restrict__ v_t,
                                                   unsigned short* __restrict__ C5) {
  __shared__ unsigned short smem[18432];   // 32KB gemm dbuf, unioned with 36.9KB Vt
  unsigned short* As = smem;               // [2][128][32]
  unsigned short* Bs = smem + 8192;        // [2][128][32]
  int tid = threadIdx.x, lane = tid & 63, wid = tid >> 6;
  long row0 = (long)blockIdx.y * 128;
  long col0 = (long)blockIdx.x * 128;
  f32x4 acc[4][4] = {};
  gemm_core_dma(A, BT, As, Bs, HID, HID, HID, row0, col0, lane, wid, acc);
  // K-loop ends with a barrier -> As/Bs dead, smem reusable for Vt.

  int wm = (wid & 1) * 64, wn = (wid >> 1) * 64;
  long row_base = row0 + wm;
  int b = (int)(row_base >> 11);
  int t_base = (int)(row_base & 2047);
  int col_base = (int)col0 + wn;
  int region = col_base >> 10;
  int l15 = lane & 15, lq = lane >> 4;

  if (region <= 1) {
    unsigned short* dst = (region == 0) ? q_r : k_r;
    float osc = (region == 0) ? SM_SCALE_LOG2E : 1.0f;
    int head = (col_base & 1023) >> 6;
    long obase = (long)(b * 16 + head) * T_ * 64;
    float fr[2];
    fr[0] = __expf(-(float)l15 * 0.28782313662425572f);
    fr[1] = __expf(-(float)(16 + l15) * 0.28782313662425572f);
#pragma unroll
    for (int m = 0; m < 4; m++) {
#pragma unroll
      for (int j = 0; j < 4; j++) {
        int t = t_base + m * 16 + lq * 4 + j;
#pragma unroll
        for (int n = 0; n < 2; n++) {
          float sn, cs;
          __sincosf((float)t * fr[n], &sn, &cs);
          float xl = acc[m][n][j], xh = acc[m][n + 2][j];
          int dd = n * 16 + l15;
          dst[obase + (long)t * 64 + dd]      = f2bf((xl * cs - xh * sn) * osc);
          dst[obase + (long)t * 64 + dd + 32] = f2bf((xl * sn + xh * cs) * osc);
        }
      }
    }
  } else if (region == 2) {
    int head = (col_base & 1023) >> 6;
    unsigned short* vt = smem + wid * 4608;
#pragma unroll
    for (int m = 0; m < 4; m++)
#pragma unroll
      for (int n = 0; n < 4; n++)
#pragma unroll
        for (int j = 0; j < 4; j++)
          vt[(n * 16 + l15) * 72 + m * 16 + lq * 4 + j] = f2bf(acc[m][n][j]);
    long obase = (long)(b * 16 + head) * 64 * T_;
#pragma unroll
    for (int i = 0; i < 8; i++) {
      int dd = i * 8 + (lane >> 3);
      int tl = (lane & 7) * 8;
      bf16x8 v = *reinterpret_cast<const bf16x8*>(&vt[dd * 72 + tl]);
      *reinterpret_cast<bf16x8*>(v_t + obase + (long)dd * T_ + t_base + tl) = v;
    }
  } else {
    int colp = col_base - 3 * HID;
#pragma unroll
    for (int m = 0; m < 4; m++) {
#pragma unroll
      for (int j = 0; j < 4; j++) {
        long row = row_base + m * 16 + lq * 4 + j;
#pragma unroll
        for (int n = 0; n < 4; n++)
          C5[row * K2 + HID + colp + n * 16 + l15] = f2bf(gelu_fast(acc[m][n][j]));
      }
    }
  }
}

// ---------------- GEMM2: C5 [8192,5120] @ w_outT [1024,5120] + bias -> f32 ----------------
__global__ __launch_bounds__(256) void gemm_bt(const unsigned short* __restrict__ A,
                                               const unsigned short* __restrict__ BT,
                                               float* __restrict__ Cout,
                                               const float* __restrict__ bias,
                                               int K, int lda, int ldb, int ldc) {
  __shared__ unsigned short smem2[16384];
  unsigned short* As = smem2;
  unsigned short* Bs = smem2 + 8192;
  int tid = threadIdx.x, lane = tid & 63, wid = tid >> 6;
  long row0 = (long)blockIdx.y * 128;
  long col0 = (long)blockIdx.x * 128;
  f32x4 acc[4][4] = {};
  gemm_core_dma(A, BT, As, Bs, K, lda, ldb, row0, col0, lane, wid, acc);
  int wm = (wid & 1) * 64, wn = (wid >> 1) * 64;
#pragma unroll
  for (int m = 0; m < 4; m++) {
#pragma unroll
    for (int n = 0; n < 4; n++) {
      long r = row0 + wm + m * 16 + (lane >> 4) * 4;
      long c = col0 + wn + n * 16 + (lane & 15);
#pragma unroll
      for (int j = 0; j < 4; j++)
        Cout[(r + j) * (long)ldc + c] = acc[m][n][j] + bias[c];
    }
  }
}

// ---------------- flash attention: R10 version (proven best: ~145 us) ----------------
__global__ __launch_bounds__(256) void attn_kernel(const unsigned short* __restrict__ q_r,
                                                   const unsigned short* __restrict__ k_r,
                                                   const unsigned short* __restrict__ v_t,
                                                   unsigned short* __restrict__ C5) {
  int qt = blockIdx.x;  // 0..15
  int bh = blockIdx.y;  // 0..63
  int b = bh >> 4, h = bh & 15;
  int tid = threadIdx.x, lane = tid & 63, wid = tid >> 6;
  int l15 = lane & 15, lq = lane >> 4;
  __shared__ unsigned short Ks[64 * 64];
  __shared__ unsigned short Vts[64 * 64];
  __shared__ unsigned short Ps[4][32 * 64];

  const unsigned short* qbase = q_r + ((long)bh * T_ + qt * 128 + wid * 32) * 64;
  bf16x8 aq[2][2];
#pragma unroll
  for (int m = 0; m < 2; m++)
#pragma unroll
    for (int kk = 0; kk < 2; kk++)
      aq[m][kk] = *reinterpret_cast<const bf16x8*>(
          qbase + (m * 16 + l15) * 64 + kk * 32 + lq * 8);

  f32x4 o_acc[2][4] = {};
  float l_run[2] = {0.f, 0.f};

  const unsigned short* kbase = k_r + (long)bh * T_ * 64;
  const unsigned short* vbase = v_t + (long)bh * 64 * T_;
  int srow = lane >> 3;
  int schnk = lane & 7;
  int slot = schnk ^ srow;
  unsigned short* Pw = &Ps[wid][0];

  bf16x8 kreg[2], vreg[2];
#pragma unroll
  for (int i = 0; i < 2; i++) {
    int c = wid * 2 + i;
    kreg[i] = *reinterpret_cast<const bf16x8*>(kbase + c * 512 + lane * 8);
    vreg[i] = *reinterpret_cast<const bf16x8*>(vbase + (long)(c * 8 + srow) * T_ + schnk * 8);
  }

  for (int kt = 0; kt < 32; kt++) {
#pragma unroll
    for (int i = 0; i < 2; i++) {
      int r = (wid * 2 + i) * 8 + srow;
      *reinterpret_cast<bf16x8*>(&Ks[r * 64 + slot * 8])  = kreg[i];
      *reinterpret_cast<bf16x8*>(&Vts[r * 64 + slot * 8]) = vreg[i];
    }
    if (kt < 31) {
#pragma unroll
      for (int i = 0; i < 2; i++) {
        int c = wid * 2 + i;
        kreg[i] = *reinterpret_cast<const bf16x8*>(kbase + (kt + 1) * 4096 + c * 512 + lane * 8);
        vreg[i] = *reinterpret_cast<const bf16x8*>(vbase + (long)(c * 8 + srow) * T_ + (kt + 1) * 64 + schnk * 8);
      }
    }
    __syncthreads();
    // S^T = K Q^T
    f32x4 s2[4][2] = {};
#pragma unroll
    for (int n = 0; n < 4; n++) {
      int krow = n * 16 + l15;
      bf16x8 kf[2];
#pragma unroll
      for (int kk = 0; kk < 2; kk++)
        kf[kk] = *reinterpret_cast<const bf16x8*>(
            &Ks[krow * 64 + ((kk * 4 + lq) ^ (krow & 7)) * 8]);
#pragma unroll
      for (int m = 0; m < 2; m++)
#pragma unroll
        for (int kk = 0; kk < 2; kk++)
          s2[n][m] = __builtin_amdgcn_mfma_f32_16x16x32_bf16(kf[kk], aq[m][kk], s2[n][m], 0, 0, 0);
    }
    // softmax: exp2, lane-local sum, pack pairs, ds_write_b64
#pragma unroll
    for (int m = 0; m < 2; m++) {
      unsigned short* prow = Pw + (m * 16 + l15) * 64;
#pragma unroll
      for (int n = 0; n < 4; n++) {
        float p0 = exp2f(s2[n][m][0]);
        float p1 = exp2f(s2[n][m][1]);
        float p2 = exp2f(s2[n][m][2]);
        float p3 = exp2f(s2[n][m][3]);
        l_run[m] += (p0 + p1) + (p2 + p3);
        unsigned int lo = cvt_pk_bf16(p0, p1);
        unsigned int hi = cvt_pk_bf16(p2, p3);
        int cc = (n * 2 + (lq >> 1)) ^ (l15 & 7);
        uint2 w; w.x = lo; w.y = hi;
        *reinterpret_cast<uint2*>(prow + cc * 8 + (lq & 1) * 4) = w;
      }
    }
    // O += P V
    bf16x8 ap[2][2];
#pragma unroll
    for (int m = 0; m < 2; m++)
#pragma unroll
      for (int kk = 0; kk < 2; kk++) {
        int cr = (kk * 4 + lq) ^ (l15 & 7);
        ap[m][kk] = *reinterpret_cast<const bf16x8*>(&Pw[(m * 16 + l15) * 64 + cr * 8]);
      }
#pragma unroll
    for (int n = 0; n < 4; n++) {
      int vrow = n * 16 + l15;
      bf16x8 bv[2];
#pragma unroll
      for (int kk = 0; kk < 2; kk++)
        bv[kk] = *reinterpret_cast<const bf16x8*>(
            &Vts[vrow * 64 + ((kk * 4 + lq) ^ (vrow & 7)) * 8]);
#pragma unroll
      for (int m = 0; m < 2; m++)
#pragma unroll
        for (int kk = 0; kk < 2; kk++)
          o_acc[m][n] = __builtin_amdgcn_mfma_f32_16x16x32_bf16(ap[m][kk], bv[kk], o_acc[m][n], 0, 0, 0);
    }
    __syncthreads();
  }
#pragma unroll
  for (int m = 0; m < 2; m++) {
    float l = l_run[m];
    l += __shfl_xor(l, 16);
    l += __shfl_xor(l, 32);
    l_run[m] = l;
  }
#pragma unroll
  for (int m = 0; m < 2; m++)
#pragma unroll
    for (int j = 0; j < 4; j++) {
      float lsum = __shfl(l_run[m], lq * 4 + j);
      float inv = 1.0f / lsum;
      int tl = qt * 128 + wid * 32 + m * 16 + lq * 4 + j;
      long row = (long)b * T_ + tl;
#pragma unroll
      for (int n = 0; n < 4; n++) {
        int col = h * 64 + n * 16 + l15;
        C5[row * K2 + col] = f2bf(o_acc[m][n][j] * inv);
      }
    }
}

extern "C" void kernel_launch(void* const* d_in, const int* in_sizes, int n_in,
                              void* d_out, int out_size, void* d_ws, size_t ws_size,
                              hipStream_t stream) {
  const float* x     = (const float*)d_in[0];
  const float* g     = (const float*)d_in[1];
  const float* be    = (const float*)d_in[2];
  const float* w_in  = (const float*)d_in[3];
  const float* w_out = (const float*)d_in[4];
  const float* b_out = (const float*)d_in[5];
  float* out = (float*)d_out;

  char* ws = (char*)d_ws;
  size_t off = 0;
  auto alloc = [&](size_t bytes) {
    void* p = ws + off;
    off += (bytes + 255) & ~(size_t)255;
    return p;
  };
  unsigned short* xn     = (unsigned short*)alloc((size_t)BT_ * HID * 2);
  unsigned short* w_inT  = (unsigned short*)alloc((size_t)N1 * HID * 2);
  unsigned short* w_outT = (unsigned short*)alloc((size_t)HID * K2 * 2);
  unsigned short* q_rb   = (unsigned short*)alloc((size_t)BT_ * HID * 2);
  unsigned short* k_rb   = (unsigned short*)alloc((size_t)BT_ * HID * 2);
  unsigned short* v_tb   = (unsigned short*)alloc((size_t)BT_ * HID * 2);
  unsigned short* C5     = (unsigned short*)alloc((size_t)BT_ * K2 * 2);

  tcast_kernel<<<dim3(N1 / 64, HID / 64), 256, 0, stream>>>(w_in, w_inT, HID, N1);
  tcast_kernel<<<dim3(HID / 64, K2 / 64), 256, 0, stream>>>(w_out, w_outT, K2, HID);
  ln_kernel<<<BT_, 256, 0, stream>>>(x, g, be, xn);
  gemm1_fused<<<dim3(N1 / 128, BT_ / 128), 256, 0, stream>>>(xn, w_inT, q_rb, k_rb, v_tb, C5);
  attn_kernel<<<dim3(T_ / 128, 64), 256, 0, stream>>>(q_rb, k_rb, v_tb, C5);
  gemm_bt<<<dim3(HID / 128, BT_ / 128), 256, 0, stream>>>(C5, w_outT, out, b_out,
                                                          K2, K2, K2, HID);
}

// Round 15
// 415.296 us; speedup vs baseline: 1.0284x; 1.0284x over previous
//
#include <hip/hip_runtime.h>
#include <hip/hip_bf16.h>
#include <math.h>

typedef short bf16x8 __attribute__((ext_vector_type(8)));
typedef float f32x4 __attribute__((ext_vector_type(4)));

#define HEADS 16
#define HDIM 64
#define HID 1024
#define B_ 4
#define T_ 2048
#define BT_ (B_*T_)      /* 8192 */
#define N1 (7*HID)       /* 7168 */
#define K2 (5*HID)       /* 5120 */

#define SM_SCALE_LOG2E 0.18033688011111793f   /* 0.125 * log2(e), folded into q at gemm1 */

__device__ __forceinline__ float bf2f(unsigned short u) {
  union { unsigned int i; float f; } c; c.i = ((unsigned int)u) << 16; return c.f;
}
__device__ __forceinline__ unsigned short f2bf(float f) {
  __hip_bfloat16 h = __float2bfloat16(f);
  return __builtin_bit_cast(unsigned short, h);
}
__device__ __forceinline__ unsigned int cvt_pk_bf16(float a, float b) {
  unsigned int r;
  asm("v_cvt_pk_bf16_f32 %0, %1, %2" : "=v"(r) : "v"(a), "v"(b));
  return r;
}
__device__ __forceinline__ float gelu_fast(float x) {
  float y = 0.7978845608028654f * (x + 0.044715f * x * x * x);
  float e = exp2f(y * 2.8853900817779268f);       // exp(2y)
  float t = 1.f - 2.f / (e + 1.f);                 // tanh(y)
  return 0.5f * x * (1.f + t);
}

// ---------------- transpose + cast: in [R][C] f32 -> out [C][R] bf16 ----------------
__global__ __launch_bounds__(256) void tcast_kernel(const float* __restrict__ in,
                                                    unsigned short* __restrict__ out,
                                                    int R, int C) {
  __shared__ float tile[64][65];
  int tx = threadIdx.x & 63;
  int ty = threadIdx.x >> 6;
  long r0 = (long)blockIdx.y * 64;
  long c0 = (long)blockIdx.x * 64;
#pragma unroll
  for (int i = 0; i < 16; i++) {
    int r = ty + i * 4;
    tile[r][tx] = in[(r0 + r) * C + c0 + tx];
  }
  __syncthreads();
#pragma unroll
  for (int i = 0; i < 16; i++) {
    int rr = ty + i * 4;
    out[(c0 + rr) * R + r0 + tx] = f2bf(tile[tx][rr]);
  }
}

// ---------------- LayerNorm f32 -> bf16 ----------------
__global__ __launch_bounds__(256) void ln_kernel(const float* __restrict__ x,
                                                 const float* __restrict__ g,
                                                 const float* __restrict__ b,
                                                 unsigned short* __restrict__ xn) {
  int row = blockIdx.x, tid = threadIdx.x;
  float4 v = reinterpret_cast<const float4*>(x + (long)row * HID)[tid];
  float s = v.x + v.y + v.z + v.w;
  float sq = v.x * v.x + v.y * v.y + v.z * v.z + v.w * v.w;
#pragma unroll
  for (int off = 32; off > 0; off >>= 1) { s += __shfl_down(s, off); sq += __shfl_down(sq, off); }
  __shared__ float red[8];
  int wid = tid >> 6, lane = tid & 63;
  if (lane == 0) { red[wid] = s; red[4 + wid] = sq; }
  __syncthreads();
  if (tid == 0) {
    red[0] = red[0] + red[1] + red[2] + red[3];
    red[4] = red[4] + red[5] + red[6] + red[7];
  }
  __syncthreads();
  float mean = red[0] * (1.f / HID);
  float var  = red[4] * (1.f / HID) - mean * mean;
  float rstd = rsqrtf(var + 1e-5f);
  float4 gv = reinterpret_cast<const float4*>(g)[tid];
  float4 bv = reinterpret_cast<const float4*>(b)[tid];
  ushort4 o;
  o.x = f2bf((v.x - mean) * rstd * gv.x + bv.x);
  o.y = f2bf((v.y - mean) * rstd * gv.y + bv.y);
  o.z = f2bf((v.z - mean) * rstd * gv.z + bv.z);
  o.w = f2bf((v.w - mean) * rstd * gv.w + bv.w);
  reinterpret_cast<ushort4*>(xn + (long)row * HID)[tid] = o;
}

// ---------------- GEMM core: 128x128, BK=32, reg-staged dbuf, single barrier ----------
// (R9/R10-proven 169 us. R14's global_load_lds variant regressed: the barrier's
// vmcnt(0) drain stalls on DMA issued only one phase earlier; reg-staging issues
// loads a full iteration ahead and tolerates the latency. Do not touch.)
__device__ __forceinline__ void gemm_core_db(const unsigned short* __restrict__ A,
                                             const unsigned short* __restrict__ BT,
                                             unsigned short* As, unsigned short* Bs,
                                             int K, int lda, int ldb,
                                             long row0, long col0,
                                             int lane, int wid, f32x4 (&acc)[4][4]) {
  int l15 = lane & 15, lq = lane >> 4;
  int srow = lane >> 2;
  int schnk = lane & 3;
  int r0s = wid * 32 + srow;
  int r1s = r0s + 16;
  int slot0 = schnk ^ ((r0s >> 1) & 3);
  int slot1 = schnk ^ ((r1s >> 1) & 3);
  const unsigned short* a0 = A + (row0 + r0s) * (long)lda + schnk * 8;
  const unsigned short* a1 = A + (row0 + r1s) * (long)lda + schnk * 8;
  const unsigned short* b0 = BT + (col0 + r0s) * (long)ldb + schnk * 8;
  const unsigned short* b1 = BT + (col0 + r1s) * (long)ldb + schnk * 8;
  int wm = (wid & 1) * 64, wn = (wid >> 1) * 64;
  int NT = K / 32;

  bf16x8 ar0 = *reinterpret_cast<const bf16x8*>(a0);
  bf16x8 ar1 = *reinterpret_cast<const bf16x8*>(a1);
  bf16x8 br0 = *reinterpret_cast<const bf16x8*>(b0);
  bf16x8 br1 = *reinterpret_cast<const bf16x8*>(b1);
  *reinterpret_cast<bf16x8*>(&As[r0s * 32 + slot0 * 8]) = ar0;
  *reinterpret_cast<bf16x8*>(&As[r1s * 32 + slot1 * 8]) = ar1;
  *reinterpret_cast<bf16x8*>(&Bs[r0s * 32 + slot0 * 8]) = br0;
  *reinterpret_cast<bf16x8*>(&Bs[r1s * 32 + slot1 * 8]) = br1;
  ar0 = *reinterpret_cast<const bf16x8*>(a0 + 32);
  ar1 = *reinterpret_cast<const bf16x8*>(a1 + 32);
  br0 = *reinterpret_cast<const bf16x8*>(b0 + 32);
  br1 = *reinterpret_cast<const bf16x8*>(b1 + 32);
  __syncthreads();

  int cur = 0;
  for (int t = 0; t < NT; t++) {
    const unsigned short* Asr = As + cur * 4096;
    const unsigned short* Bsr = Bs + cur * 4096;
    bf16x8 af[4], bfv[4];
#pragma unroll
    for (int m = 0; m < 4; m++) {
      int r = wm + m * 16 + l15;
      af[m] = *reinterpret_cast<const bf16x8*>(&Asr[r * 32 + (lq ^ ((r >> 1) & 3)) * 8]);
    }
#pragma unroll
    for (int n = 0; n < 4; n++) {
      int r = wn + n * 16 + l15;
      bfv[n] = *reinterpret_cast<const bf16x8*>(&Bsr[r * 32 + (lq ^ ((r >> 1) & 3)) * 8]);
    }
    if (t + 1 < NT) {
      unsigned short* Asw = As + (cur ^ 1) * 4096;
      unsigned short* Bsw = Bs + (cur ^ 1) * 4096;
      *reinterpret_cast<bf16x8*>(&Asw[r0s * 32 + slot0 * 8]) = ar0;
      *reinterpret_cast<bf16x8*>(&Asw[r1s * 32 + slot1 * 8]) = ar1;
      *reinterpret_cast<bf16x8*>(&Bsw[r0s * 32 + slot0 * 8]) = br0;
      *reinterpret_cast<bf16x8*>(&Bsw[r1s * 32 + slot1 * 8]) = br1;
    }
    if (t + 2 < NT) {
      long ko = (long)(t + 2) * 32;
      ar0 = *reinterpret_cast<const bf16x8*>(a0 + ko);
      ar1 = *reinterpret_cast<const bf16x8*>(a1 + ko);
      br0 = *reinterpret_cast<const bf16x8*>(b0 + ko);
      br1 = *reinterpret_cast<const bf16x8*>(b1 + ko);
    }
#pragma unroll
    for (int m = 0; m < 4; m++)
#pragma unroll
      for (int n = 0; n < 4; n++)
        acc[m][n] = __builtin_amdgcn_mfma_f32_16x16x32_bf16(af[m], bfv[n], acc[m][n], 0, 0, 0);
    __syncthreads();
    cur ^= 1;
  }
}

// ---------------- GEMM1 with fused rotary / V-transpose / GELU epilogue (R10) ----------
__global__ __launch_bounds__(256) void gemm1_fused(const unsigned short* __restrict__ A,
                                                   const unsigned short* __restrict__ BT,
                                                   unsigned short* __restrict__ q_r,
                                                   unsigned short* __restrict__ k_r,
                                                   unsigned short* __restrict__ v_t,
                                                   unsigned short* __restrict__ C5) {
  __shared__ unsigned short smem[18432];
  unsigned short* As = smem;
  unsigned short* Bs = smem + 8192;
  int tid = threadIdx.x, lane = tid & 63, wid = tid >> 6;
  long row0 = (long)blockIdx.y * 128;
  long col0 = (long)blockIdx.x * 128;
  f32x4 acc[4][4] = {};
  gemm_core_db(A, BT, As, Bs, HID, HID, HID, row0, col0, lane, wid, acc);

  int wm = (wid & 1) * 64, wn = (wid >> 1) * 64;
  long row_base = row0 + wm;
  int b = (int)(row_base >> 11);
  int t_base = (int)(row_base & 2047);
  int col_base = (int)col0 + wn;
  int region = col_base >> 10;
  int l15 = lane & 15, lq = lane >> 4;

  if (region <= 1) {
    unsigned short* dst = (region == 0) ? q_r : k_r;
    float osc = (region == 0) ? SM_SCALE_LOG2E : 1.0f;
    int head = (col_base & 1023) >> 6;
    long obase = (long)(b * 16 + head) * T_ * 64;
    float fr[2];
    fr[0] = __expf(-(float)l15 * 0.28782313662425572f);
    fr[1] = __expf(-(float)(16 + l15) * 0.28782313662425572f);
#pragma unroll
    for (int m = 0; m < 4; m++) {
#pragma unroll
      for (int j = 0; j < 4; j++) {
        int t = t_base + m * 16 + lq * 4 + j;
#pragma unroll
        for (int n = 0; n < 2; n++) {
          float sn, cs;
          __sincosf((float)t * fr[n], &sn, &cs);
          float xl = acc[m][n][j], xh = acc[m][n + 2][j];
          int d = n * 16 + l15;
          dst[obase + (long)t * 64 + d]      = f2bf((xl * cs - xh * sn) * osc);
          dst[obase + (long)t * 64 + d + 32] = f2bf((xl * sn + xh * cs) * osc);
        }
      }
    }
  } else if (region == 2) {
    int head = (col_base & 1023) >> 6;
    unsigned short* vt = smem + wid * 4608;
#pragma unroll
    for (int m = 0; m < 4; m++)
#pragma unroll
      for (int n = 0; n < 4; n++)
#pragma unroll
        for (int j = 0; j < 4; j++)
          vt[(n * 16 + l15) * 72 + m * 16 + lq * 4 + j] = f2bf(acc[m][n][j]);
    long obase = (long)(b * 16 + head) * 64 * T_;
#pragma unroll
    for (int i = 0; i < 8; i++) {
      int d = i * 8 + (lane >> 3);
      int tl = (lane & 7) * 8;
      bf16x8 v = *reinterpret_cast<const bf16x8*>(&vt[d * 72 + tl]);
      *reinterpret_cast<bf16x8*>(v_t + obase + (long)d * T_ + t_base + tl) = v;
    }
  } else {
    int colp = col_base - 3 * HID;
#pragma unroll
    for (int m = 0; m < 4; m++) {
#pragma unroll
      for (int j = 0; j < 4; j++) {
        long row = row_base + m * 16 + lq * 4 + j;
#pragma unroll
        for (int n = 0; n < 4; n++)
          C5[row * K2 + HID + colp + n * 16 + l15] = f2bf(gelu_fast(acc[m][n][j]));
      }
    }
  }
}

// ---------------- GEMM2: C5 [8192,5120] @ w_outT [1024,5120] + bias -> f32 ----------------
__global__ __launch_bounds__(256) void gemm_bt(const unsigned short* __restrict__ A,
                                               const unsigned short* __restrict__ BT,
                                               float* __restrict__ Cout,
                                               const float* __restrict__ bias,
                                               int K, int lda, int ldb, int ldc) {
  __shared__ unsigned short smem2[16384];
  unsigned short* As = smem2;
  unsigned short* Bs = smem2 + 8192;
  int tid = threadIdx.x, lane = tid & 63, wid = tid >> 6;
  long row0 = (long)blockIdx.y * 128;
  long col0 = (long)blockIdx.x * 128;
  f32x4 acc[4][4] = {};
  gemm_core_db(A, BT, As, Bs, K, lda, ldb, row0, col0, lane, wid, acc);
  int wm = (wid & 1) * 64, wn = (wid >> 1) * 64;
#pragma unroll
  for (int m = 0; m < 4; m++) {
#pragma unroll
    for (int n = 0; n < 4; n++) {
      long r = row0 + wm + m * 16 + (lane >> 4) * 4;
      long c = col0 + wn + n * 16 + (lane & 15);
#pragma unroll
      for (int j = 0; j < 4; j++)
        Cout[(r + j) * (long)ldc + c] = acc[m][n][j] + bias[c];
    }
  }
}

// ---------------- flash attention: R10 core + XCD-locality grid + setprio ----------
// Grid (x=bh 64, y=qt 16): linear id = qt*64+bh -> XCD = bh%8, so all 16 q-blocks of
// a bh share one XCD; per-XCD K/V working set = 8 bh x 512KB = 4MB = one L2. K/V
// re-reads become ~200cy L2 hits, not ~900cy HBM misses (attn is latency-bound:
// MfmaUtil 16%, LDS ~30%, VALU ~30%, nothing saturated). R5's test of this grid was
// confounded by VGPR-spill; this is the clean test. s_setprio(1) around MFMA
// clusters (T5: +4-7% for multi-block latency-bound attn, m191).
__global__ __launch_bounds__(256) void attn_kernel(const unsigned short* __restrict__ q_r,
                                                   const unsigned short* __restrict__ k_r,
                                                   const unsigned short* __restrict__ v_t,
                                                   unsigned short* __restrict__ C5) {
  int bh = blockIdx.x;  // 0..63  (XCD-locality axis)
  int qt = blockIdx.y;  // 0..15
  int b = bh >> 4, h = bh & 15;
  int tid = threadIdx.x, lane = tid & 63, wid = tid >> 6;
  int l15 = lane & 15, lq = lane >> 4;
  __shared__ unsigned short Ks[64 * 64];
  __shared__ unsigned short Vts[64 * 64];
  __shared__ unsigned short Ps[4][32 * 64];

  const unsigned short* qbase = q_r + ((long)bh * T_ + qt * 128 + wid * 32) * 64;
  bf16x8 aq[2][2];
#pragma unroll
  for (int m = 0; m < 2; m++)
#pragma unroll
    for (int kk = 0; kk < 2; kk++)
      aq[m][kk] = *reinterpret_cast<const bf16x8*>(
          qbase + (m * 16 + l15) * 64 + kk * 32 + lq * 8);

  f32x4 o_acc[2][4] = {};
  float l_run[2] = {0.f, 0.f};

  const unsigned short* kbase = k_r + (long)bh * T_ * 64;
  const unsigned short* vbase = v_t + (long)bh * 64 * T_;
  int srow = lane >> 3;
  int schnk = lane & 7;
  int slot = schnk ^ srow;
  unsigned short* Pw = &Ps[wid][0];

  bf16x8 kreg[2], vreg[2];
#pragma unroll
  for (int i = 0; i < 2; i++) {
    int c = wid * 2 + i;
    kreg[i] = *reinterpret_cast<const bf16x8*>(kbase + c * 512 + lane * 8);
    vreg[i] = *reinterpret_cast<const bf16x8*>(vbase + (long)(c * 8 + srow) * T_ + schnk * 8);
  }

  for (int kt = 0; kt < 32; kt++) {
#pragma unroll
    for (int i = 0; i < 2; i++) {
      int r = (wid * 2 + i) * 8 + srow;
      *reinterpret_cast<bf16x8*>(&Ks[r * 64 + slot * 8])  = kreg[i];
      *reinterpret_cast<bf16x8*>(&Vts[r * 64 + slot * 8]) = vreg[i];
    }
    if (kt < 31) {
#pragma unroll
      for (int i = 0; i < 2; i++) {
        int c = wid * 2 + i;
        kreg[i] = *reinterpret_cast<const bf16x8*>(kbase + (kt + 1) * 4096 + c * 512 + lane * 8);
        vreg[i] = *reinterpret_cast<const bf16x8*>(vbase + (long)(c * 8 + srow) * T_ + (kt + 1) * 64 + schnk * 8);
      }
    }
    __syncthreads();
    // S^T = K Q^T
    f32x4 s2[4][2] = {};
    __builtin_amdgcn_s_setprio(1);
#pragma unroll
    for (int n = 0; n < 4; n++) {
      int krow = n * 16 + l15;
      bf16x8 kf[2];
#pragma unroll
      for (int kk = 0; kk < 2; kk++)
        kf[kk] = *reinterpret_cast<const bf16x8*>(
            &Ks[krow * 64 + ((kk * 4 + lq) ^ (krow & 7)) * 8]);
#pragma unroll
      for (int m = 0; m < 2; m++)
#pragma unroll
        for (int kk = 0; kk < 2; kk++)
          s2[n][m] = __builtin_amdgcn_mfma_f32_16x16x32_bf16(kf[kk], aq[m][kk], s2[n][m], 0, 0, 0);
    }
    __builtin_amdgcn_s_setprio(0);
    // softmax: exp2, lane-local sum, pack pairs, ds_write_b64
#pragma unroll
    for (int m = 0; m < 2; m++) {
      unsigned short* prow = Pw + (m * 16 + l15) * 64;
#pragma unroll
      for (int n = 0; n < 4; n++) {
        float p0 = exp2f(s2[n][m][0]);
        float p1 = exp2f(s2[n][m][1]);
        float p2 = exp2f(s2[n][m][2]);
        float p3 = exp2f(s2[n][m][3]);
        l_run[m] += (p0 + p1) + (p2 + p3);
        unsigned int lo = cvt_pk_bf16(p0, p1);
        unsigned int hi = cvt_pk_bf16(p2, p3);
        int cc = (n * 2 + (lq >> 1)) ^ (l15 & 7);
        uint2 w; w.x = lo; w.y = hi;
        *reinterpret_cast<uint2*>(prow + cc * 8 + (lq & 1) * 4) = w;
      }
    }
    // O += P V
    bf16x8 ap[2][2];
#pragma unroll
    for (int m = 0; m < 2; m++)
#pragma unroll
      for (int kk = 0; kk < 2; kk++) {
        int cr = (kk * 4 + lq) ^ (l15 & 7);
        ap[m][kk] = *reinterpret_cast<const bf16x8*>(&Pw[(m * 16 + l15) * 64 + cr * 8]);
      }
    __builtin_amdgcn_s_setprio(1);
#pragma unroll
    for (int n = 0; n < 4; n++) {
      int vrow = n * 16 + l15;
      bf16x8 bv[2];
#pragma unroll
      for (int kk = 0; kk < 2; kk++)
        bv[kk] = *reinterpret_cast<const bf16x8*>(
            &Vts[vrow * 64 + ((kk * 4 + lq) ^ (vrow & 7)) * 8]);
#pragma unroll
      for (int m = 0; m < 2; m++)
#pragma unroll
        for (int kk = 0; kk < 2; kk++)
          o_acc[m][n] = __builtin_amdgcn_mfma_f32_16x16x32_bf16(ap[m][kk], bv[kk], o_acc[m][n], 0, 0, 0);
    }
    __builtin_amdgcn_s_setprio(0);
    __syncthreads();
  }
#pragma unroll
  for (int m = 0; m < 2; m++) {
    float l = l_run[m];
    l += __shfl_xor(l, 16);
    l += __shfl_xor(l, 32);
    l_run[m] = l;
  }
#pragma unroll
  for (int m = 0; m < 2; m++)
#pragma unroll
    for (int j = 0; j < 4; j++) {
      float lsum = __shfl(l_run[m], lq * 4 + j);
      float inv = 1.0f / lsum;
      int tl = qt * 128 + wid * 32 + m * 16 + lq * 4 + j;
      long row = (long)b * T_ + tl;
#pragma unroll
      for (int n = 0; n < 4; n++) {
        int col = h * 64 + n * 16 + l15;
        C5[row * K2 + col] = f2bf(o_acc[m][n][j] * inv);
      }
    }
}

extern "C" void kernel_launch(void* const* d_in, const int* in_sizes, int n_in,
                              void* d_out, int out_size, void* d_ws, size_t ws_size,
                              hipStream_t stream) {
  const float* x     = (const float*)d_in[0];
  const float* g     = (const float*)d_in[1];
  const float* be    = (const float*)d_in[2];
  const float* w_in  = (const float*)d_in[3];
  const float* w_out = (const float*)d_in[4];
  const float* b_out = (const float*)d_in[5];
  float* out = (float*)d_out;

  char* ws = (char*)d_ws;
  size_t off = 0;
  auto alloc = [&](size_t bytes) {
    void* p = ws + off;
    off += (bytes + 255) & ~(size_t)255;
    return p;
  };
  unsigned short* xn     = (unsigned short*)alloc((size_t)BT_ * HID * 2);
  unsigned short* w_inT  = (unsigned short*)alloc((size_t)N1 * HID * 2);
  unsigned short* w_outT = (unsigned short*)alloc((size_t)HID * K2 * 2);
  unsigned short* q_rb   = (unsigned short*)alloc((size_t)BT_ * HID * 2);
  unsigned short* k_rb   = (unsigned short*)alloc((size_t)BT_ * HID * 2);
  unsigned short* v_tb   = (unsigned short*)alloc((size_t)BT_ * HID * 2);
  unsigned short* C5     = (unsigned short*)alloc((size_t)BT_ * K2 * 2);

  tcast_kernel<<<dim3(N1 / 64, HID / 64), 256, 0, stream>>>(w_in, w_inT, HID, N1);
  tcast_kernel<<<dim3(HID / 64, K2 / 64), 256, 0, stream>>>(w_out, w_outT, K2, HID);
  ln_kernel<<<BT_, 256, 0, stream>>>(x, g, be, xn);
  gemm1_fused<<<dim3(N1 / 128, BT_ / 128), 256, 0, stream>>>(xn, w_inT, q_rb, k_rb, v_tb, C5);
  attn_kernel<<<dim3(64, T_ / 128), 256, 0, stream>>>(q_rb, k_rb, v_tb, C5);
  gemm_bt<<<dim3(HID / 128, BT_ / 128), 256, 0, stream>>>(C5, w_outT, out, b_out,
                                                          K2, K2, K2, HID);
}

// Round 16
// 412.310 us; speedup vs baseline: 1.0358x; 1.0072x over previous
//
#include <hip/hip_runtime.h>
#include <hip/hip_bf16.h>
#include <math.h>

typedef short bf16x8 __attribute__((ext_vector_type(8)));
typedef float f32x4 __attribute__((ext_vector_type(4)));
typedef float f32x16 __attribute__((ext_vector_type(16)));

#define HEADS 16
#define HDIM 64
#define HID 1024
#define B_ 4
#define T_ 2048
#define BT_ (B_*T_)      /* 8192 */
#define N1 (7*HID)       /* 7168 */
#define K2 (5*HID)       /* 5120 */

#define SM_SCALE_LOG2E 0.18033688011111793f   /* 0.125 * log2(e), folded into q at gemm1 */

__device__ __forceinline__ float bf2f(unsigned short u) {
  union { unsigned int i; float f; } c; c.i = ((unsigned int)u) << 16; return c.f;
}
__device__ __forceinline__ unsigned short f2bf(float f) {
  __hip_bfloat16 h = __float2bfloat16(f);
  return __builtin_bit_cast(unsigned short, h);
}
__device__ __forceinline__ unsigned int cvt_pk_bf16(float a, float b) {
  unsigned int r;
  asm("v_cvt_pk_bf16_f32 %0, %1, %2" : "=v"(r) : "v"(a), "v"(b));
  return r;
}
// v_permlane32_swap_b32: D.lanes[32:63] <-> S.lanes[0:31]; writes BOTH regs.
__device__ __forceinline__ void permswap(unsigned int& d, unsigned int& s) {
  asm volatile("v_permlane32_swap_b32 %0, %1" : "+v"(d), "+v"(s));
}
__device__ __forceinline__ float gelu_fast(float x) {
  float y = 0.7978845608028654f * (x + 0.044715f * x * x * x);
  float e = exp2f(y * 2.8853900817779268f);       // exp(2y)
  float t = 1.f - 2.f / (e + 1.f);                 // tanh(y)
  return 0.5f * x * (1.f + t);
}

// ---------------- transpose + cast: in [R][C] f32 -> out [C][R] bf16 ----------------
__global__ __launch_bounds__(256) void tcast_kernel(const float* __restrict__ in,
                                                    unsigned short* __restrict__ out,
                                                    int R, int C) {
  __shared__ float tile[64][65];
  int tx = threadIdx.x & 63;
  int ty = threadIdx.x >> 6;
  long r0 = (long)blockIdx.y * 64;
  long c0 = (long)blockIdx.x * 64;
#pragma unroll
  for (int i = 0; i < 16; i++) {
    int r = ty + i * 4;
    tile[r][tx] = in[(r0 + r) * C + c0 + tx];
  }
  __syncthreads();
#pragma unroll
  for (int i = 0; i < 16; i++) {
    int rr = ty + i * 4;
    out[(c0 + rr) * R + r0 + tx] = f2bf(tile[tx][rr]);
  }
}

// ---------------- LayerNorm f32 -> bf16 ----------------
__global__ __launch_bounds__(256) void ln_kernel(const float* __restrict__ x,
                                                 const float* __restrict__ g,
                                                 const float* __restrict__ b,
                                                 unsigned short* __restrict__ xn) {
  int row = blockIdx.x, tid = threadIdx.x;
  float4 v = reinterpret_cast<const float4*>(x + (long)row * HID)[tid];
  float s = v.x + v.y + v.z + v.w;
  float sq = v.x * v.x + v.y * v.y + v.z * v.z + v.w * v.w;
#pragma unroll
  for (int off = 32; off > 0; off >>= 1) { s += __shfl_down(s, off); sq += __shfl_down(sq, off); }
  __shared__ float red[8];
  int wid = tid >> 6, lane = tid & 63;
  if (lane == 0) { red[wid] = s; red[4 + wid] = sq; }
  __syncthreads();
  if (tid == 0) {
    red[0] = red[0] + red[1] + red[2] + red[3];
    red[4] = red[4] + red[5] + red[6] + red[7];
  }
  __syncthreads();
  float mean = red[0] * (1.f / HID);
  float var  = red[4] * (1.f / HID) - mean * mean;
  float rstd = rsqrtf(var + 1e-5f);
  float4 gv = reinterpret_cast<const float4*>(g)[tid];
  float4 bv = reinterpret_cast<const float4*>(b)[tid];
  ushort4 o;
  o.x = f2bf((v.x - mean) * rstd * gv.x + bv.x);
  o.y = f2bf((v.y - mean) * rstd * gv.y + bv.y);
  o.z = f2bf((v.z - mean) * rstd * gv.z + bv.z);
  o.w = f2bf((v.w - mean) * rstd * gv.w + bv.w);
  reinterpret_cast<ushort4*>(xn + (long)row * HID)[tid] = o;
}

// ---------------- GEMM core: 128x128, BK=32, reg-staged dbuf, single barrier ----------
// (R9/R10-proven 169 us. Do not touch.)
__device__ __forceinline__ void gemm_core_db(const unsigned short* __restrict__ A,
                                             const unsigned short* __restrict__ BT,
                                             unsigned short* As, unsigned short* Bs,
                                             int K, int lda, int ldb,
                                             long row0, long col0,
                                             int lane, int wid, f32x4 (&acc)[4][4]) {
  int l15 = lane & 15, lq = lane >> 4;
  int srow = lane >> 2;
  int schnk = lane & 3;
  int r0s = wid * 32 + srow;
  int r1s = r0s + 16;
  int slot0 = schnk ^ ((r0s >> 1) & 3);
  int slot1 = schnk ^ ((r1s >> 1) & 3);
  const unsigned short* a0 = A + (row0 + r0s) * (long)lda + schnk * 8;
  const unsigned short* a1 = A + (row0 + r1s) * (long)lda + schnk * 8;
  const unsigned short* b0 = BT + (col0 + r0s) * (long)ldb + schnk * 8;
  const unsigned short* b1 = BT + (col0 + r1s) * (long)ldb + schnk * 8;
  int wm = (wid & 1) * 64, wn = (wid >> 1) * 64;
  int NT = K / 32;

  bf16x8 ar0 = *reinterpret_cast<const bf16x8*>(a0);
  bf16x8 ar1 = *reinterpret_cast<const bf16x8*>(a1);
  bf16x8 br0 = *reinterpret_cast<const bf16x8*>(b0);
  bf16x8 br1 = *reinterpret_cast<const bf16x8*>(b1);
  *reinterpret_cast<bf16x8*>(&As[r0s * 32 + slot0 * 8]) = ar0;
  *reinterpret_cast<bf16x8*>(&As[r1s * 32 + slot1 * 8]) = ar1;
  *reinterpret_cast<bf16x8*>(&Bs[r0s * 32 + slot0 * 8]) = br0;
  *reinterpret_cast<bf16x8*>(&Bs[r1s * 32 + slot1 * 8]) = br1;
  ar0 = *reinterpret_cast<const bf16x8*>(a0 + 32);
  ar1 = *reinterpret_cast<const bf16x8*>(a1 + 32);
  br0 = *reinterpret_cast<const bf16x8*>(b0 + 32);
  br1 = *reinterpret_cast<const bf16x8*>(b1 + 32);
  __syncthreads();

  int cur = 0;
  for (int t = 0; t < NT; t++) {
    const unsigned short* Asr = As + cur * 4096;
    const unsigned short* Bsr = Bs + cur * 4096;
    bf16x8 af[4], bfv[4];
#pragma unroll
    for (int m = 0; m < 4; m++) {
      int r = wm + m * 16 + l15;
      af[m] = *reinterpret_cast<const bf16x8*>(&Asr[r * 32 + (lq ^ ((r >> 1) & 3)) * 8]);
    }
#pragma unroll
    for (int n = 0; n < 4; n++) {
      int r = wn + n * 16 + l15;
      bfv[n] = *reinterpret_cast<const bf16x8*>(&Bsr[r * 32 + (lq ^ ((r >> 1) & 3)) * 8]);
    }
    if (t + 1 < NT) {
      unsigned short* Asw = As + (cur ^ 1) * 4096;
      unsigned short* Bsw = Bs + (cur ^ 1) * 4096;
      *reinterpret_cast<bf16x8*>(&Asw[r0s * 32 + slot0 * 8]) = ar0;
      *reinterpret_cast<bf16x8*>(&Asw[r1s * 32 + slot1 * 8]) = ar1;
      *reinterpret_cast<bf16x8*>(&Bsw[r0s * 32 + slot0 * 8]) = br0;
      *reinterpret_cast<bf16x8*>(&Bsw[r1s * 32 + slot1 * 8]) = br1;
    }
    if (t + 2 < NT) {
      long ko = (long)(t + 2) * 32;
      ar0 = *reinterpret_cast<const bf16x8*>(a0 + ko);
      ar1 = *reinterpret_cast<const bf16x8*>(a1 + ko);
      br0 = *reinterpret_cast<const bf16x8*>(b0 + ko);
      br1 = *reinterpret_cast<const bf16x8*>(b1 + ko);
    }
#pragma unroll
    for (int m = 0; m < 4; m++)
#pragma unroll
      for (int n = 0; n < 4; n++)
        acc[m][n] = __builtin_amdgcn_mfma_f32_16x16x32_bf16(af[m], bfv[n], acc[m][n], 0, 0, 0);
    __syncthreads();
    cur ^= 1;
  }
}

// ---------------- GEMM1 with fused rotary / V-transpose / GELU epilogue (R10) ----------
__global__ __launch_bounds__(256) void gemm1_fused(const unsigned short* __restrict__ A,
                                                   const unsigned short* __restrict__ BT,
                                                   unsigned short* __restrict__ q_r,
                                                   unsigned short* __restrict__ k_r,
                                                   unsigned short* __restrict__ v_t,
                                                   unsigned short* __restrict__ C5) {
  __shared__ unsigned short smem[18432];
  unsigned short* As = smem;
  unsigned short* Bs = smem + 8192;
  int tid = threadIdx.x, lane = tid & 63, wid = tid >> 6;
  long row0 = (long)blockIdx.y * 128;
  long col0 = (long)blockIdx.x * 128;
  f32x4 acc[4][4] = {};
  gemm_core_db(A, BT, As, Bs, HID, HID, HID, row0, col0, lane, wid, acc);

  int wm = (wid & 1) * 64, wn = (wid >> 1) * 64;
  long row_base = row0 + wm;
  int b = (int)(row_base >> 11);
  int t_base = (int)(row_base & 2047);
  int col_base = (int)col0 + wn;
  int region = col_base >> 10;
  int l15 = lane & 15, lq = lane >> 4;

  if (region <= 1) {
    unsigned short* dst = (region == 0) ? q_r : k_r;
    float osc = (region == 0) ? SM_SCALE_LOG2E : 1.0f;
    int head = (col_base & 1023) >> 6;
    long obase = (long)(b * 16 + head) * T_ * 64;
    float fr[2];
    fr[0] = __expf(-(float)l15 * 0.28782313662425572f);
    fr[1] = __expf(-(float)(16 + l15) * 0.28782313662425572f);
#pragma unroll
    for (int m = 0; m < 4; m++) {
#pragma unroll
      for (int j = 0; j < 4; j++) {
        int t = t_base + m * 16 + lq * 4 + j;
#pragma unroll
        for (int n = 0; n < 2; n++) {
          float sn, cs;
          __sincosf((float)t * fr[n], &sn, &cs);
          float xl = acc[m][n][j], xh = acc[m][n + 2][j];
          int d = n * 16 + l15;
          dst[obase + (long)t * 64 + d]      = f2bf((xl * cs - xh * sn) * osc);
          dst[obase + (long)t * 64 + d + 32] = f2bf((xl * sn + xh * cs) * osc);
        }
      }
    }
  } else if (region == 2) {
    int head = (col_base & 1023) >> 6;
    unsigned short* vt = smem + wid * 4608;
#pragma unroll
    for (int m = 0; m < 4; m++)
#pragma unroll
      for (int n = 0; n < 4; n++)
#pragma unroll
        for (int j = 0; j < 4; j++)
          vt[(n * 16 + l15) * 72 + m * 16 + lq * 4 + j] = f2bf(acc[m][n][j]);
    long obase = (long)(b * 16 + head) * 64 * T_;
#pragma unroll
    for (int i = 0; i < 8; i++) {
      int d = i * 8 + (lane >> 3);
      int tl = (lane & 7) * 8;
      bf16x8 v = *reinterpret_cast<const bf16x8*>(&vt[d * 72 + tl]);
      *reinterpret_cast<bf16x8*>(v_t + obase + (long)d * T_ + t_base + tl) = v;
    }
  } else {
    int colp = col_base - 3 * HID;
#pragma unroll
    for (int m = 0; m < 4; m++) {
#pragma unroll
      for (int j = 0; j < 4; j++) {
        long row = row_base + m * 16 + lq * 4 + j;
#pragma unroll
        for (int n = 0; n < 4; n++)
          C5[row * K2 + HID + colp + n * 16 + l15] = f2bf(gelu_fast(acc[m][n][j]));
      }
    }
  }
}

// ---------------- GEMM2: C5 [8192,5120] @ w_outT [1024,5120] + bias -> f32 ----------------
__global__ __launch_bounds__(256) void gemm_bt(const unsigned short* __restrict__ A,
                                               const unsigned short* __restrict__ BT,
                                               float* __restrict__ Cout,
                                               const float* __restrict__ bias,
                                               int K, int lda, int ldb, int ldc) {
  __shared__ unsigned short smem2[16384];
  unsigned short* As = smem2;
  unsigned short* Bs = smem2 + 8192;
  int tid = threadIdx.x, lane = tid & 63, wid = tid >> 6;
  long row0 = (long)blockIdx.y * 128;
  long col0 = (long)blockIdx.x * 128;
  f32x4 acc[4][4] = {};
  gemm_core_db(A, BT, As, Bs, K, lda, ldb, row0, col0, lane, wid, acc);
  int wm = (wid & 1) * 64, wn = (wid >> 1) * 64;
#pragma unroll
  for (int m = 0; m < 4; m++) {
#pragma unroll
    for (int n = 0; n < 4; n++) {
      long r = row0 + wm + m * 16 + (lane >> 4) * 4;
      long c = col0 + wn + n * 16 + (lane & 15);
#pragma unroll
      for (int j = 0; j < 4; j++)
        Cout[(r + j) * (long)ldc + c] = acc[m][n][j] + bias[c];
    }
  }
}

// ---------------- flash attention: 32x32 MFMA, in-register P, dbuf K/V, 1 barrier/kt --
// attn was LDS-pipe-bound (16 waves x ~32 LDS instr/kt ~= 5400 cy/CU/kt >> 620 MFMA).
// This version: swapped QK^T via mfma_32x32x16 (S^T: col=lane&31=q lane-resident ->
// l_run is ONE scalar; rows k=(reg&3)+8(reg>>2)+4hi per m74/m101). P stays in regs:
// cvt_pk pairs + v_permlane32_swap redistribute k-halves (swap(g0p0,g1p0)->c0,c2 etc),
// feeding PV's A-operand (A[row=lane&31=q][k=hi*8+e]) directly. V LDS already [d][k].
// LDS/wave/kt: 20 b128 (4 staged writes + 8 K-reads + 8 V-reads), was 32 instrs; P
// buffer (16KB) deleted; K/V double-buffered -> ONE barrier/kt (was 2). LDS 32KB.
__global__ __launch_bounds__(256) void attn_kernel(const unsigned short* __restrict__ q_r,
                                                   const unsigned short* __restrict__ k_r,
                                                   const unsigned short* __restrict__ v_t,
                                                   unsigned short* __restrict__ C5) {
  int bh = blockIdx.x;  // 0..63 (XCD-locality axis)
  int qt = blockIdx.y;  // 0..15
  int b = bh >> 4, h = bh & 15;
  int tid = threadIdx.x, lane = tid & 63, wid = tid >> 6;
  int l31 = lane & 31, hi = lane >> 5;
  __shared__ unsigned short Ks[2][64 * 64];
  __shared__ unsigned short Vts[2][64 * 64];

  // Q fragments (B-operand): lane holds Q[q=l31][kd = kk*16 + hi*8 + e]
  const unsigned short* qbase = q_r + ((long)bh * T_ + qt * 128 + wid * 32) * 64;
  bf16x8 qf[4];
#pragma unroll
  for (int kk = 0; kk < 4; kk++)
    qf[kk] = *reinterpret_cast<const bf16x8*>(qbase + l31 * 64 + kk * 16 + hi * 8);

  f32x16 o_acc[2] = {};
  float l_run = 0.f;

  const unsigned short* kbase = k_r + (long)bh * T_ * 64;
  const unsigned short* vbase = v_t + (long)bh * 64 * T_;
  int srow = lane >> 3;          // 0..7 within 8-row staging segment
  int schnk = lane & 7;          // 16B chunk (monotonic -> coalesced)
  int slot = schnk ^ srow;       // LDS slot: chunk c of row r at c^(r&7)

  // prologue: stage kt0 -> buf0; prefetch kt1 -> regs
  bf16x8 kreg[2], vreg[2];
#pragma unroll
  for (int i = 0; i < 2; i++) {
    int c = wid * 2 + i;
    kreg[i] = *reinterpret_cast<const bf16x8*>(kbase + c * 512 + lane * 8);
    vreg[i] = *reinterpret_cast<const bf16x8*>(vbase + (long)(c * 8 + srow) * T_ + schnk * 8);
  }
#pragma unroll
  for (int i = 0; i < 2; i++) {
    int r = (wid * 2 + i) * 8 + srow;
    *reinterpret_cast<bf16x8*>(&Ks[0][r * 64 + slot * 8])  = kreg[i];
    *reinterpret_cast<bf16x8*>(&Vts[0][r * 64 + slot * 8]) = vreg[i];
  }
#pragma unroll
  for (int i = 0; i < 2; i++) {
    int c = wid * 2 + i;
    kreg[i] = *reinterpret_cast<const bf16x8*>(kbase + 4096 + c * 512 + lane * 8);
    vreg[i] = *reinterpret_cast<const bf16x8*>(vbase + (long)(c * 8 + srow) * T_ + 64 + schnk * 8);
  }
  __syncthreads();

  int cur = 0;
  for (int kt = 0; kt < 32; kt++) {
    // write staged tile kt+1 into the other buffer (no reader this iteration)
    if (kt < 31) {
#pragma unroll
      for (int i = 0; i < 2; i++) {
        int r = (wid * 2 + i) * 8 + srow;
        *reinterpret_cast<bf16x8*>(&Ks[cur ^ 1][r * 64 + slot * 8])  = kreg[i];
        *reinterpret_cast<bf16x8*>(&Vts[cur ^ 1][r * 64 + slot * 8]) = vreg[i];
      }
    }
    // issue loads for tile kt+2 (full compute phase to cover latency)
    if (kt < 30) {
#pragma unroll
      for (int i = 0; i < 2; i++) {
        int c = wid * 2 + i;
        kreg[i] = *reinterpret_cast<const bf16x8*>(kbase + (kt + 2) * 4096 + c * 512 + lane * 8);
        vreg[i] = *reinterpret_cast<const bf16x8*>(vbase + (long)(c * 8 + srow) * T_ + (kt + 2) * 64 + schnk * 8);
      }
    }
    const unsigned short* Kc = Ks[cur];
    const unsigned short* Vc = Vts[cur];

    // per 32-k tile: S^T = K Q^T (32x32x16), softmax, pack to PV A-frags
    bf16x8 pa[4];
#pragma unroll
    for (int t2 = 0; t2 < 2; t2++) {
      f32x16 s2 = {};
      int krow = t2 * 32 + l31;
      __builtin_amdgcn_s_setprio(1);
#pragma unroll
      for (int kk = 0; kk < 4; kk++) {
        int c = kk * 2 + hi;
        bf16x8 kf = *reinterpret_cast<const bf16x8*>(&Kc[krow * 64 + (c ^ (krow & 7)) * 8]);
        s2 = __builtin_amdgcn_mfma_f32_32x32x16_bf16(kf, qf[kk], s2, 0, 0, 0);
      }
      __builtin_amdgcn_s_setprio(0);
      float p[16];
#pragma unroll
      for (int r = 0; r < 16; r++) p[r] = exp2f(s2[r]);
#pragma unroll
      for (int r = 0; r < 16; r++) l_run += p[r];
      unsigned int g0 = cvt_pk_bf16(p[0],  p[1]);
      unsigned int g1 = cvt_pk_bf16(p[2],  p[3]);
      unsigned int g2 = cvt_pk_bf16(p[4],  p[5]);
      unsigned int g3 = cvt_pk_bf16(p[6],  p[7]);
      unsigned int g4 = cvt_pk_bf16(p[8],  p[9]);
      unsigned int g5 = cvt_pk_bf16(p[10], p[11]);
      unsigned int g6 = cvt_pk_bf16(p[12], p[13]);
      unsigned int g7 = cvt_pk_bf16(p[14], p[15]);
      permswap(g0, g2);   // -> c0 (k 8hi+0,1), c2 (k 8hi+4,5) of chunk 2*t2
      permswap(g1, g3);   // -> c1, c3
      permswap(g4, g6);   // chunk 2*t2+1
      permswap(g5, g7);
      uint4 u0; u0.x = g0; u0.y = g1; u0.z = g2; u0.w = g3;
      uint4 u1; u1.x = g4; u1.y = g5; u1.z = g6; u1.w = g7;
      pa[t2 * 2]     = __builtin_bit_cast(bf16x8, u0);
      pa[t2 * 2 + 1] = __builtin_bit_cast(bf16x8, u1);
    }
    // O += P V  (A=pa in regs, B=V from LDS [d][k])
    __builtin_amdgcn_s_setprio(1);
#pragma unroll
    for (int dt = 0; dt < 2; dt++) {
      int vrow = dt * 32 + l31;
#pragma unroll
      for (int kc = 0; kc < 4; kc++) {
        int c = kc * 2 + hi;
        bf16x8 vf = *reinterpret_cast<const bf16x8*>(&Vc[vrow * 64 + (c ^ (vrow & 7)) * 8]);
        o_acc[dt] = __builtin_amdgcn_mfma_f32_32x32x16_bf16(pa[kc], vf, o_acc[dt], 0, 0, 0);
      }
    }
    __builtin_amdgcn_s_setprio(0);
    __syncthreads();
    cur ^= 1;
  }
  // epilogue: l complete after one half-swap (hi halves own complementary k's)
  float l = l_run;
  l += __shfl_xor(l, 32);
#pragma unroll
  for (int r = 0; r < 16; r++) {
    int qr = (r & 3) + 8 * (r >> 2) + 4 * hi;
    float inv = 1.0f / __shfl(l, qr);        // lane qr holds full sum for q=qr
    int tl = qt * 128 + wid * 32 + qr;
    long row = (long)b * T_ + tl;
#pragma unroll
    for (int dt = 0; dt < 2; dt++) {
      int col = h * 64 + dt * 32 + l31;
      C5[row * K2 + col] = f2bf(o_acc[dt][r] * inv);
    }
  }
}

extern "C" void kernel_launch(void* const* d_in, const int* in_sizes, int n_in,
                              void* d_out, int out_size, void* d_ws, size_t ws_size,
                              hipStream_t stream) {
  const float* x     = (const float*)d_in[0];
  const float* g     = (const float*)d_in[1];
  const float* be    = (const float*)d_in[2];
  const float* w_in  = (const float*)d_in[3];
  const float* w_out = (const float*)d_in[4];
  const float* b_out = (const float*)d_in[5];
  float* out = (float*)d_out;

  char* ws = (char*)d_ws;
  size_t off = 0;
  auto alloc = [&](size_t bytes) {
    void* p = ws + off;
    off += (bytes + 255) & ~(size_t)255;
    return p;
  };
  unsigned short* xn     = (unsigned short*)alloc((size_t)BT_ * HID * 2);
  unsigned short* w_inT  = (unsigned short*)alloc((size_t)N1 * HID * 2);
  unsigned short* w_outT = (unsigned short*)alloc((size_t)HID * K2 * 2);
  unsigned short* q_rb   = (unsigned short*)alloc((size_t)BT_ * HID * 2);
  unsigned short* k_rb   = (unsigned short*)alloc((size_t)BT_ * HID * 2);
  unsigned short* v_tb   = (unsigned short*)alloc((size_t)BT_ * HID * 2);
  unsigned short* C5     = (unsigned short*)alloc((size_t)BT_ * K2 * 2);

  tcast_kernel<<<dim3(N1 / 64, HID / 64), 256, 0, stream>>>(w_in, w_inT, HID, N1);
  tcast_kernel<<<dim3(HID / 64, K2 / 64), 256, 0, stream>>>(w_out, w_outT, K2, HID);
  ln_kernel<<<BT_, 256, 0, stream>>>(x, g, be, xn);
  gemm1_fused<<<dim3(N1 / 128, BT_ / 128), 256, 0, stream>>>(xn, w_inT, q_rb, k_rb, v_tb, C5);
  attn_kernel<<<dim3(64, T_ / 128), 256, 0, stream>>>(q_rb, k_rb, v_tb, C5);
  gemm_bt<<<dim3(HID / 128, BT_ / 128), 256, 0, stream>>>(C5, w_outT, out, b_out,
                                                          K2, K2, K2, HID);
}

// Round 17
// 406.869 us; speedup vs baseline: 1.0497x; 1.0134x over previous
//
#include <hip/hip_runtime.h>
#include <hip/hip_bf16.h>
#include <math.h>

typedef short bf16x8 __attribute__((ext_vector_type(8)));
typedef float f32x4 __attribute__((ext_vector_type(4)));
typedef float f32x16 __attribute__((ext_vector_type(16)));

#define HEADS 16
#define HDIM 64
#define HID 1024
#define B_ 4
#define T_ 2048
#define BT_ (B_*T_)      /* 8192 */
#define N1 (7*HID)       /* 7168 */
#define K2 (5*HID)       /* 5120 */

#define SM_SCALE_LOG2E 0.18033688011111793f   /* 0.125 * log2(e), folded into q at gemm1 */

__device__ __forceinline__ float bf2f(unsigned short u) {
  union { unsigned int i; float f; } c; c.i = ((unsigned int)u) << 16; return c.f;
}
__device__ __forceinline__ unsigned short f2bf(float f) {
  __hip_bfloat16 h = __float2bfloat16(f);
  return __builtin_bit_cast(unsigned short, h);
}
__device__ __forceinline__ unsigned int cvt_pk_bf16(float a, float b) {
  unsigned int r;
  asm("v_cvt_pk_bf16_f32 %0, %1, %2" : "=v"(r) : "v"(a), "v"(b));
  return r;
}
// v_permlane32_swap_b32: D.lanes[32:63] <-> S.lanes[0:31]; writes BOTH regs.
__device__ __forceinline__ void permswap(unsigned int& d, unsigned int& s) {
  asm volatile("v_permlane32_swap_b32 %0, %1" : "+v"(d), "+v"(s));
}
__device__ __forceinline__ float gelu_fast(float x) {
  float y = 0.7978845608028654f * (x + 0.044715f * x * x * x);
  float e = exp2f(y * 2.8853900817779268f);       // exp(2y)
  float t = 1.f - 2.f / (e + 1.f);                 // tanh(y)
  return 0.5f * x * (1.f + t);
}

// ---------------- transpose + cast: in [R][C] f32 -> out [C][R] bf16 ----------------
__global__ __launch_bounds__(256) void tcast_kernel(const float* __restrict__ in,
                                                    unsigned short* __restrict__ out,
                                                    int R, int C) {
  __shared__ float tile[64][65];
  int tx = threadIdx.x & 63;
  int ty = threadIdx.x >> 6;
  long r0 = (long)blockIdx.y * 64;
  long c0 = (long)blockIdx.x * 64;
#pragma unroll
  for (int i = 0; i < 16; i++) {
    int r = ty + i * 4;
    tile[r][tx] = in[(r0 + r) * C + c0 + tx];
  }
  __syncthreads();
#pragma unroll
  for (int i = 0; i < 16; i++) {
    int rr = ty + i * 4;
    out[(c0 + rr) * R + r0 + tx] = f2bf(tile[tx][rr]);
  }
}

// ---------------- LayerNorm f32 -> bf16 ----------------
__global__ __launch_bounds__(256) void ln_kernel(const float* __restrict__ x,
                                                 const float* __restrict__ g,
                                                 const float* __restrict__ b,
                                                 unsigned short* __restrict__ xn) {
  int row = blockIdx.x, tid = threadIdx.x;
  float4 v = reinterpret_cast<const float4*>(x + (long)row * HID)[tid];
  float s = v.x + v.y + v.z + v.w;
  float sq = v.x * v.x + v.y * v.y + v.z * v.z + v.w * v.w;
#pragma unroll
  for (int off = 32; off > 0; off >>= 1) { s += __shfl_down(s, off); sq += __shfl_down(sq, off); }
  __shared__ float red[8];
  int wid = tid >> 6, lane = tid & 63;
  if (lane == 0) { red[wid] = s; red[4 + wid] = sq; }
  __syncthreads();
  if (tid == 0) {
    red[0] = red[0] + red[1] + red[2] + red[3];
    red[4] = red[4] + red[5] + red[6] + red[7];
  }
  __syncthreads();
  float mean = red[0] * (1.f / HID);
  float var  = red[4] * (1.f / HID) - mean * mean;
  float rstd = rsqrtf(var + 1e-5f);
  float4 gv = reinterpret_cast<const float4*>(g)[tid];
  float4 bv = reinterpret_cast<const float4*>(b)[tid];
  ushort4 o;
  o.x = f2bf((v.x - mean) * rstd * gv.x + bv.x);
  o.y = f2bf((v.y - mean) * rstd * gv.y + bv.y);
  o.z = f2bf((v.z - mean) * rstd * gv.z + bv.z);
  o.w = f2bf((v.w - mean) * rstd * gv.w + bv.w);
  reinterpret_cast<ushort4*>(xn + (long)row * HID)[tid] = o;
}

// ---------------- GEMM1: 256x128 tile, 8 waves, BK=32, reg-staged dbuf, 1 barrier ------
// Traffic analysis (R17): 128^2 core is tile-traffic-bound (L2->CU 64KB/CU-round vs
// MFMA 307cy). BM=256/BN=128 keeps the PROVEN per-wave 64x64 acc[4][4] fragment code
// (wave grid 4Mx2N) while cutting per-output L2+LDS-write traffic 27%. LDS 48KB ->
// 3 blocks/CU (no 256^2-style 1-block lockstep). V epilogue: packed cvt_pk direct
// stores (R11-verified), no Vt LDS.
__global__ __launch_bounds__(512) void gemm1_fused(const unsigned short* __restrict__ A,
                                                   const unsigned short* __restrict__ BT,
                                                   unsigned short* __restrict__ q_r,
                                                   unsigned short* __restrict__ k_r,
                                                   unsigned short* __restrict__ v_t,
                                                   unsigned short* __restrict__ C5) {
  __shared__ unsigned short As[2 * 256 * 32];   // 32KB
  __shared__ unsigned short Bs[2 * 128 * 32];   // 16KB
  int tid = threadIdx.x, lane = tid & 63, wid = tid >> 6;
  int l15 = lane & 15, lq = lane >> 4;
  int wr = wid >> 1, wc = wid & 1;              // 4M x 2N wave grid
  long row0 = (long)blockIdx.y * 256;
  long col0 = (long)blockIdx.x * 128;
  f32x4 acc[4][4] = {};

  // staging: A 256 rows x 4 chunks (2 per thread), B 128 rows x 4 chunks (1 per thread)
  int sr0 = tid >> 2;                 // 0..127
  int sr1 = sr0 + 128;
  int sch = tid & 3;
  int sl0 = sch ^ ((sr0 >> 1) & 3);
  int sl1 = sch ^ ((sr1 >> 1) & 3);
  const unsigned short* a0 = A + (row0 + sr0) * (long)HID + sch * 8;
  const unsigned short* a1 = A + (row0 + sr1) * (long)HID + sch * 8;
  const unsigned short* b0 = BT + (col0 + sr0) * (long)HID + sch * 8;

  // prologue: tile0 -> regs -> buf0; tile1 -> regs
  bf16x8 ar0 = *reinterpret_cast<const bf16x8*>(a0);
  bf16x8 ar1 = *reinterpret_cast<const bf16x8*>(a1);
  bf16x8 br0 = *reinterpret_cast<const bf16x8*>(b0);
  *reinterpret_cast<bf16x8*>(&As[sr0 * 32 + sl0 * 8]) = ar0;
  *reinterpret_cast<bf16x8*>(&As[sr1 * 32 + sl1 * 8]) = ar1;
  *reinterpret_cast<bf16x8*>(&Bs[sr0 * 32 + sl0 * 8]) = br0;
  ar0 = *reinterpret_cast<const bf16x8*>(a0 + 32);
  ar1 = *reinterpret_cast<const bf16x8*>(a1 + 32);
  br0 = *reinterpret_cast<const bf16x8*>(b0 + 32);
  __syncthreads();

  const int NT = HID / 32;   // 32
  int cur = 0;
  for (int t = 0; t < NT; t++) {
    const unsigned short* Asr = As + cur * 8192;
    const unsigned short* Bsr = Bs + cur * 4096;
    bf16x8 af[4], bfv[4];
#pragma unroll
    for (int m = 0; m < 4; m++) {
      int r = wr * 64 + m * 16 + l15;
      af[m] = *reinterpret_cast<const bf16x8*>(&Asr[r * 32 + (lq ^ ((r >> 1) & 3)) * 8]);
    }
#pragma unroll
    for (int n = 0; n < 4; n++) {
      int r = wc * 64 + n * 16 + l15;
      bfv[n] = *reinterpret_cast<const bf16x8*>(&Bsr[r * 32 + (lq ^ ((r >> 1) & 3)) * 8]);
    }
    if (t + 1 < NT) {
      unsigned short* Asw = As + (cur ^ 1) * 8192;
      unsigned short* Bsw = Bs + (cur ^ 1) * 4096;
      *reinterpret_cast<bf16x8*>(&Asw[sr0 * 32 + sl0 * 8]) = ar0;
      *reinterpret_cast<bf16x8*>(&Asw[sr1 * 32 + sl1 * 8]) = ar1;
      *reinterpret_cast<bf16x8*>(&Bsw[sr0 * 32 + sl0 * 8]) = br0;
    }
    if (t + 2 < NT) {
      long ko = (long)(t + 2) * 32;
      ar0 = *reinterpret_cast<const bf16x8*>(a0 + ko);
      ar1 = *reinterpret_cast<const bf16x8*>(a1 + ko);
      br0 = *reinterpret_cast<const bf16x8*>(b0 + ko);
    }
#pragma unroll
    for (int m = 0; m < 4; m++)
#pragma unroll
      for (int n = 0; n < 4; n++)
        acc[m][n] = __builtin_amdgcn_mfma_f32_16x16x32_bf16(af[m], bfv[n], acc[m][n], 0, 0, 0);
    __syncthreads();
    cur ^= 1;
  }

  // ---- epilogue (per-wave 64 rows x 64 cols; same region math as R10) ----
  long row_base = row0 + wr * 64;            // 64-aligned
  int b = (int)(row_base >> 11);
  int t_base = (int)(row_base & 2047);
  int col_base = (int)col0 + wc * 64;        // 64-aligned, one head/region per wave
  int region = col_base >> 10;               // 0=q 1=k 2=v 3..6=p
  int head = (col_base & 1023) >> 6;

  if (region <= 1) {
    unsigned short* dst = (region == 0) ? q_r : k_r;
    float osc = (region == 0) ? SM_SCALE_LOG2E : 1.0f;
    long obase = (long)(b * 16 + head) * T_ * 64;
    float fr[2];
    fr[0] = __expf(-(float)l15 * 0.28782313662425572f);          // 10000^(-d/32)
    fr[1] = __expf(-(float)(16 + l15) * 0.28782313662425572f);
#pragma unroll
    for (int m = 0; m < 4; m++) {
#pragma unroll
      for (int j = 0; j < 4; j++) {
        int t = t_base + m * 16 + lq * 4 + j;
#pragma unroll
        for (int n = 0; n < 2; n++) {
          float sn, cs;
          __sincosf((float)t * fr[n], &sn, &cs);
          float xl = acc[m][n][j], xh = acc[m][n + 2][j];
          int d = n * 16 + l15;
          dst[obase + (long)t * 64 + d]      = f2bf((xl * cs - xh * sn) * osc);
          dst[obase + (long)t * 64 + d + 32] = f2bf((xl * sn + xh * cs) * osc);
        }
      }
    }
  } else if (region == 2) {
    // V: packed direct stores (R11-verified), v_t[bh][d][t0..t0+3], no LDS
    long obase = (long)(b * 16 + head) * 64 * T_;
#pragma unroll
    for (int m = 0; m < 4; m++) {
      int t0 = t_base + m * 16 + lq * 4;
#pragma unroll
      for (int n = 0; n < 4; n++) {
        int d = n * 16 + l15;
        uint2 w;
        w.x = cvt_pk_bf16(acc[m][n][0], acc[m][n][1]);
        w.y = cvt_pk_bf16(acc[m][n][2], acc[m][n][3]);
        *reinterpret_cast<uint2*>(v_t + obase + (long)d * T_ + t0) = w;
      }
    }
  } else {
    int colp = col_base - 3 * HID;
#pragma unroll
    for (int m = 0; m < 4; m++) {
#pragma unroll
      for (int j = 0; j < 4; j++) {
        long row = row_base + m * 16 + lq * 4 + j;
#pragma unroll
        for (int n = 0; n < 4; n++)
          C5[row * K2 + HID + colp + n * 16 + l15] = f2bf(gelu_fast(acc[m][n][j]));
      }
    }
  }
}

// ---------------- GEMM2 core (128x128, R9-proven; do not touch) ----------------
__device__ __forceinline__ void gemm_core_db(const unsigned short* __restrict__ A,
                                             const unsigned short* __restrict__ BT,
                                             unsigned short* As, unsigned short* Bs,
                                             int K, int lda, int ldb,
                                             long row0, long col0,
                                             int lane, int wid, f32x4 (&acc)[4][4]) {
  int l15 = lane & 15, lq = lane >> 4;
  int srow = lane >> 2;
  int schnk = lane & 3;
  int r0s = wid * 32 + srow;
  int r1s = r0s + 16;
  int slot0 = schnk ^ ((r0s >> 1) & 3);
  int slot1 = schnk ^ ((r1s >> 1) & 3);
  const unsigned short* a0 = A + (row0 + r0s) * (long)lda + schnk * 8;
  const unsigned short* a1 = A + (row0 + r1s) * (long)lda + schnk * 8;
  const unsigned short* b0 = BT + (col0 + r0s) * (long)ldb + schnk * 8;
  const unsigned short* b1 = BT + (col0 + r1s) * (long)ldb + schnk * 8;
  int wm = (wid & 1) * 64, wn = (wid >> 1) * 64;
  int NT = K / 32;

  bf16x8 ar0 = *reinterpret_cast<const bf16x8*>(a0);
  bf16x8 ar1 = *reinterpret_cast<const bf16x8*>(a1);
  bf16x8 br0 = *reinterpret_cast<const bf16x8*>(b0);
  bf16x8 br1 = *reinterpret_cast<const bf16x8*>(b1);
  *reinterpret_cast<bf16x8*>(&As[r0s * 32 + slot0 * 8]) = ar0;
  *reinterpret_cast<bf16x8*>(&As[r1s * 32 + slot1 * 8]) = ar1;
  *reinterpret_cast<bf16x8*>(&Bs[r0s * 32 + slot0 * 8]) = br0;
  *reinterpret_cast<bf16x8*>(&Bs[r1s * 32 + slot1 * 8]) = br1;
  ar0 = *reinterpret_cast<const bf16x8*>(a0 + 32);
  ar1 = *reinterpret_cast<const bf16x8*>(a1 + 32);
  br0 = *reinterpret_cast<const bf16x8*>(b0 + 32);
  br1 = *reinterpret_cast<const bf16x8*>(b1 + 32);
  __syncthreads();

  int cur = 0;
  for (int t = 0; t < NT; t++) {
    const unsigned short* Asr = As + cur * 4096;
    const unsigned short* Bsr = Bs + cur * 4096;
    bf16x8 af[4], bfv[4];
#pragma unroll
    for (int m = 0; m < 4; m++) {
      int r = wm + m * 16 + l15;
      af[m] = *reinterpret_cast<const bf16x8*>(&Asr[r * 32 + (lq ^ ((r >> 1) & 3)) * 8]);
    }
#pragma unroll
    for (int n = 0; n < 4; n++) {
      int r = wn + n * 16 + l15;
      bfv[n] = *reinterpret_cast<const bf16x8*>(&Bsr[r * 32 + (lq ^ ((r >> 1) & 3)) * 8]);
    }
    if (t + 1 < NT) {
      unsigned short* Asw = As + (cur ^ 1) * 4096;
      unsigned short* Bsw = Bs + (cur ^ 1) * 4096;
      *reinterpret_cast<bf16x8*>(&Asw[r0s * 32 + slot0 * 8]) = ar0;
      *reinterpret_cast<bf16x8*>(&Asw[r1s * 32 + slot1 * 8]) = ar1;
      *reinterpret_cast<bf16x8*>(&Bsw[r0s * 32 + slot0 * 8]) = br0;
      *reinterpret_cast<bf16x8*>(&Bsw[r1s * 32 + slot1 * 8]) = br1;
    }
    if (t + 2 < NT) {
      long ko = (long)(t + 2) * 32;
      ar0 = *reinterpret_cast<const bf16x8*>(a0 + ko);
      ar1 = *reinterpret_cast<const bf16x8*>(a1 + ko);
      br0 = *reinterpret_cast<const bf16x8*>(b0 + ko);
      br1 = *reinterpret_cast<const bf16x8*>(b1 + ko);
    }
#pragma unroll
    for (int m = 0; m < 4; m++)
#pragma unroll
      for (int n = 0; n < 4; n++)
        acc[m][n] = __builtin_amdgcn_mfma_f32_16x16x32_bf16(af[m], bfv[n], acc[m][n], 0, 0, 0);
    __syncthreads();
    cur ^= 1;
  }
}

// ---------------- GEMM2: C5 [8192,5120] @ w_outT [1024,5120] + bias -> f32 ----------------
__global__ __launch_bounds__(256) void gemm_bt(const unsigned short* __restrict__ A,
                                               const unsigned short* __restrict__ BT,
                                               float* __restrict__ Cout,
                                               const float* __restrict__ bias,
                                               int K, int lda, int ldb, int ldc) {
  __shared__ unsigned short smem2[16384];
  unsigned short* As = smem2;
  unsigned short* Bs = smem2 + 8192;
  int tid = threadIdx.x, lane = tid & 63, wid = tid >> 6;
  long row0 = (long)blockIdx.y * 128;
  long col0 = (long)blockIdx.x * 128;
  f32x4 acc[4][4] = {};
  gemm_core_db(A, BT, As, Bs, K, lda, ldb, row0, col0, lane, wid, acc);
  int wm = (wid & 1) * 64, wn = (wid >> 1) * 64;
#pragma unroll
  for (int m = 0; m < 4; m++) {
#pragma unroll
    for (int n = 0; n < 4; n++) {
      long r = row0 + wm + m * 16 + (lane >> 4) * 4;
      long c = col0 + wn + n * 16 + (lane & 15);
#pragma unroll
      for (int j = 0; j < 4; j++)
        Cout[(r + j) * (long)ldc + c] = acc[m][n][j] + bias[c];
    }
  }
}

// ---------------- flash attention: 32x32 MFMA, in-register P (R16, proven) ----------
__global__ __launch_bounds__(256) void attn_kernel(const unsigned short* __restrict__ q_r,
                                                   const unsigned short* __restrict__ k_r,
                                                   const unsigned short* __restrict__ v_t,
                                                   unsigned short* __restrict__ C5) {
  int bh = blockIdx.x;  // 0..63 (XCD-locality axis)
  int qt = blockIdx.y;  // 0..15
  int b = bh >> 4, h = bh & 15;
  int tid = threadIdx.x, lane = tid & 63, wid = tid >> 6;
  int l31 = lane & 31, hi = lane >> 5;
  __shared__ unsigned short Ks[2][64 * 64];
  __shared__ unsigned short Vts[2][64 * 64];

  const unsigned short* qbase = q_r + ((long)bh * T_ + qt * 128 + wid * 32) * 64;
  bf16x8 qf[4];
#pragma unroll
  for (int kk = 0; kk < 4; kk++)
    qf[kk] = *reinterpret_cast<const bf16x8*>(qbase + l31 * 64 + kk * 16 + hi * 8);

  f32x16 o_acc[2] = {};
  float l_run = 0.f;

  const unsigned short* kbase = k_r + (long)bh * T_ * 64;
  const unsigned short* vbase = v_t + (long)bh * 64 * T_;
  int srow = lane >> 3;
  int schnk = lane & 7;
  int slot = schnk ^ srow;

  bf16x8 kreg[2], vreg[2];
#pragma unroll
  for (int i = 0; i < 2; i++) {
    int c = wid * 2 + i;
    kreg[i] = *reinterpret_cast<const bf16x8*>(kbase + c * 512 + lane * 8);
    vreg[i] = *reinterpret_cast<const bf16x8*>(vbase + (long)(c * 8 + srow) * T_ + schnk * 8);
  }
#pragma unroll
  for (int i = 0; i < 2; i++) {
    int r = (wid * 2 + i) * 8 + srow;
    *reinterpret_cast<bf16x8*>(&Ks[0][r * 64 + slot * 8])  = kreg[i];
    *reinterpret_cast<bf16x8*>(&Vts[0][r * 64 + slot * 8]) = vreg[i];
  }
#pragma unroll
  for (int i = 0; i < 2; i++) {
    int c = wid * 2 + i;
    kreg[i] = *reinterpret_cast<const bf16x8*>(kbase + 4096 + c * 512 + lane * 8);
    vreg[i] = *reinterpret_cast<const bf16x8*>(vbase + (long)(c * 8 + srow) * T_ + 64 + schnk * 8);
  }
  __syncthreads();

  int cur = 0;
  for (int kt = 0; kt < 32; kt++) {
    if (kt < 31) {
#pragma unroll
      for (int i = 0; i < 2; i++) {
        int r = (wid * 2 + i) * 8 + srow;
        *reinterpret_cast<bf16x8*>(&Ks[cur ^ 1][r * 64 + slot * 8])  = kreg[i];
        *reinterpret_cast<bf16x8*>(&Vts[cur ^ 1][r * 64 + slot * 8]) = vreg[i];
      }
    }
    if (kt < 30) {
#pragma unroll
      for (int i = 0; i < 2; i++) {
        int c = wid * 2 + i;
        kreg[i] = *reinterpret_cast<const bf16x8*>(kbase + (kt + 2) * 4096 + c * 512 + lane * 8);
        vreg[i] = *reinterpret_cast<const bf16x8*>(vbase + (long)(c * 8 + srow) * T_ + (kt + 2) * 64 + schnk * 8);
      }
    }
    const unsigned short* Kc = Ks[cur];
    const unsigned short* Vc = Vts[cur];

    bf16x8 pa[4];
#pragma unroll
    for (int t2 = 0; t2 < 2; t2++) {
      f32x16 s2 = {};
      int krow = t2 * 32 + l31;
      __builtin_amdgcn_s_setprio(1);
#pragma unroll
      for (int kk = 0; kk < 4; kk++) {
        int c = kk * 2 + hi;
        bf16x8 kf = *reinterpret_cast<const bf16x8*>(&Kc[krow * 64 + (c ^ (krow & 7)) * 8]);
        s2 = __builtin_amdgcn_mfma_f32_32x32x16_bf16(kf, qf[kk], s2, 0, 0, 0);
      }
      __builtin_amdgcn_s_setprio(0);
      float p[16];
#pragma unroll
      for (int r = 0; r < 16; r++) p[r] = exp2f(s2[r]);
#pragma unroll
      for (int r = 0; r < 16; r++) l_run += p[r];
      unsigned int g0 = cvt_pk_bf16(p[0],  p[1]);
      unsigned int g1 = cvt_pk_bf16(p[2],  p[3]);
      unsigned int g2 = cvt_pk_bf16(p[4],  p[5]);
      unsigned int g3 = cvt_pk_bf16(p[6],  p[7]);
      unsigned int g4 = cvt_pk_bf16(p[8],  p[9]);
      unsigned int g5 = cvt_pk_bf16(p[10], p[11]);
      unsigned int g6 = cvt_pk_bf16(p[12], p[13]);
      unsigned int g7 = cvt_pk_bf16(p[14], p[15]);
      permswap(g0, g2);
      permswap(g1, g3);
      permswap(g4, g6);
      permswap(g5, g7);
      uint4 u0; u0.x = g0; u0.y = g1; u0.z = g2; u0.w = g3;
      uint4 u1; u1.x = g4; u1.y = g5; u1.z = g6; u1.w = g7;
      pa[t2 * 2]     = __builtin_bit_cast(bf16x8, u0);
      pa[t2 * 2 + 1] = __builtin_bit_cast(bf16x8, u1);
    }
    __builtin_amdgcn_s_setprio(1);
#pragma unroll
    for (int dt = 0; dt < 2; dt++) {
      int vrow = dt * 32 + l31;
#pragma unroll
      for (int kc = 0; kc < 4; kc++) {
        int c = kc * 2 + hi;
        bf16x8 vf = *reinterpret_cast<const bf16x8*>(&Vc[vrow * 64 + (c ^ (vrow & 7)) * 8]);
        o_acc[dt] = __builtin_amdgcn_mfma_f32_32x32x16_bf16(pa[kc], vf, o_acc[dt], 0, 0, 0);
      }
    }
    __builtin_amdgcn_s_setprio(0);
    __syncthreads();
    cur ^= 1;
  }
  float l = l_run;
  l += __shfl_xor(l, 32);
#pragma unroll
  for (int r = 0; r < 16; r++) {
    int qr = (r & 3) + 8 * (r >> 2) + 4 * hi;
    float inv = 1.0f / __shfl(l, qr);
    int tl = qt * 128 + wid * 32 + qr;
    long row = (long)b * T_ + tl;
#pragma unroll
    for (int dt = 0; dt < 2; dt++) {
      int col = h * 64 + dt * 32 + l31;
      C5[row * K2 + col] = f2bf(o_acc[dt][r] * inv);
    }
  }
}

extern "C" void kernel_launch(void* const* d_in, const int* in_sizes, int n_in,
                              void* d_out, int out_size, void* d_ws, size_t ws_size,
                              hipStream_t stream) {
  const float* x     = (const float*)d_in[0];
  const float* g     = (const float*)d_in[1];
  const float* be    = (const float*)d_in[2];
  const float* w_in  = (const float*)d_in[3];
  const float* w_out = (const float*)d_in[4];
  const float* b_out = (const float*)d_in[5];
  float* out = (float*)d_out;

  char* ws = (char*)d_ws;
  size_t off = 0;
  auto alloc = [&](size_t bytes) {
    void* p = ws + off;
    off += (bytes + 255) & ~(size_t)255;
    return p;
  };
  unsigned short* xn     = (unsigned short*)alloc((size_t)BT_ * HID * 2);
  unsigned short* w_inT  = (unsigned short*)alloc((size_t)N1 * HID * 2);
  unsigned short* w_outT = (unsigned short*)alloc((size_t)HID * K2 * 2);
  unsigned short* q_rb   = (unsigned short*)alloc((size_t)BT_ * HID * 2);
  unsigned short* k_rb   = (unsigned short*)alloc((size_t)BT_ * HID * 2);
  unsigned short* v_tb   = (unsigned short*)alloc((size_t)BT_ * HID * 2);
  unsigned short* C5     = (unsigned short*)alloc((size_t)BT_ * K2 * 2);

  tcast_kernel<<<dim3(N1 / 64, HID / 64), 256, 0, stream>>>(w_in, w_inT, HID, N1);
  tcast_kernel<<<dim3(HID / 64, K2 / 64), 256, 0, stream>>>(w_out, w_outT, K2, HID);
  ln_kernel<<<BT_, 256, 0, stream>>>(x, g, be, xn);
  gemm1_fused<<<dim3(N1 / 128, BT_ / 256), 512, 0, stream>>>(xn, w_inT, q_rb, k_rb, v_tb, C5);
  attn_kernel<<<dim3(64, T_ / 128), 256, 0, stream>>>(q_rb, k_rb, v_tb, C5);
  gemm_bt<<<dim3(HID / 128, BT_ / 128), 256, 0, stream>>>(C5, w_outT, out, b_out,
                                                          K2, K2, K2, HID);
}